// Round 1
// baseline (855.520 us; speedup 1.0000x reference)
//
#include <hip/hip_runtime.h>
#include <math.h>

#define T_TOK 1024
#define DIMM  512      // model dim
#define EDIM  1024     // expert hidden
#define HIDD  256      // micro hidden
#define NEXP  8
#define NMIC  325
#define ETILES 136     // max expert tiles (16-pair)
#define MTILES 840     // max micro tiles (16-pair)

__device__ __forceinline__ float dot4(float4 a, float4 b) {
    return a.x*b.x + a.y*b.y + a.z*b.z + a.w*b.w;
}
__device__ __forceinline__ float gelu_exact(float x) {
    return 0.5f * x * (1.0f + erff(x * 0.70710678118654752f));
}
__device__ __forceinline__ float wave_sum(float v) {
    #pragma unroll
    for (int o = 32; o; o >>= 1) v += __shfl_xor(v, o);
    return v;
}

// ---------------- expert router: softmax over 8, top-2, renorm ----------------
__global__ void k_router(const float* __restrict__ x, const float* __restrict__ rw,
                         const float* __restrict__ rb, int* __restrict__ eidx,
                         float* __restrict__ ew, int* __restrict__ ecnt) {
    int wave = threadIdx.x >> 6, lane = threadIdx.x & 63;
    int t = blockIdx.x * 4 + wave;
    if (t >= T_TOK) return;
    const float* xr = x + (size_t)t * DIMM;
    float xv[8];
    #pragma unroll
    for (int j = 0; j < 8; ++j) xv[j] = xr[lane + 64*j];
    float p[NEXP];
    #pragma unroll
    for (int e = 0; e < NEXP; ++e) {
        const float* wr = rw + (size_t)e * DIMM;
        float a = 0.f;
        #pragma unroll
        for (int j = 0; j < 8; ++j) a += xv[j] * wr[lane + 64*j];
        p[e] = wave_sum(a) + rb[e];
    }
    float m = p[0];
    #pragma unroll
    for (int e = 1; e < NEXP; ++e) m = fmaxf(m, p[e]);
    float Z = 0.f;
    #pragma unroll
    for (int e = 0; e < NEXP; ++e) { p[e] = expf(p[e] - m); Z += p[e]; }
    #pragma unroll
    for (int e = 0; e < NEXP; ++e) p[e] /= Z;
    int i1 = 0; float v1 = p[0];
    #pragma unroll
    for (int e = 1; e < NEXP; ++e) if (p[e] > v1) { v1 = p[e]; i1 = e; }
    int i2 = -1; float v2 = -1.f;
    #pragma unroll
    for (int e = 0; e < NEXP; ++e) if (e != i1 && p[e] > v2) { v2 = p[e]; i2 = e; }
    float s = v1 + v2 + 1e-8f;
    if (lane == 0) {
        eidx[t*2] = i1; eidx[t*2+1] = i2;
        ew[t*2] = v1 / s; ew[t*2+1] = v2 / s;
        atomicAdd(&ecnt[i1], 1); atomicAdd(&ecnt[i2], 1);
    }
}

// ---------------- generic scan + tile builder (1 block, 512 threads) ----------------
__global__ void k_scan(const int* __restrict__ cnt, int n, int pm,
                       int* __restrict__ off, int* __restrict__ cur,
                       int2* __restrict__ tiles, int* __restrict__ ntile) {
    __shared__ int s[512], s2[512];
    int tid = threadIdx.x;
    int v  = (tid < n) ? cnt[tid] : 0;
    int tc = (v + pm - 1) / pm;
    s[tid] = v; s2[tid] = tc;
    __syncthreads();
    for (int d = 1; d < 512; d <<= 1) {
        int a = (tid >= d) ? s[tid-d] : 0;
        int b = (tid >= d) ? s2[tid-d] : 0;
        __syncthreads();
        s[tid] += a; s2[tid] += b;
        __syncthreads();
    }
    int myoff = s[tid] - v, tb = s2[tid] - tc;
    if (tid < n) { off[tid] = myoff; cur[tid] = myoff; }
    if (tid == n-1) off[n] = s[tid];
    if (tid == 511) *ntile = s2[511];
    for (int j = 0; j < tc; ++j) tiles[tb + j] = make_int2(tid, myoff + j*pm);
}

// ---------------- generic scatter ----------------
__global__ void k_scatter(const int* __restrict__ idx, const float* __restrict__ w,
                          int total, int S, int* __restrict__ cur,
                          int* __restrict__ ptok, float* __restrict__ pw) {
    int g = blockIdx.x * blockDim.x + threadIdx.x;
    if (g >= total) return;
    int t = g / S;
    int e = idx[g];
    int pos = atomicAdd(&cur[e], 1);
    ptok[pos] = t; pw[pos] = w[g];
}

// ---------------- expert FFN1: h = gelu(X @ W1^T + b1) ----------------
__global__ __launch_bounds__(256) void k_effn1(
    const float* __restrict__ x, const float* __restrict__ w1, const float* __restrict__ b1,
    const int2* __restrict__ tiles, const int* __restrict__ ntile,
    const int* __restrict__ eoff, const int* __restrict__ ep_tok,
    float* __restrict__ hbuf) {
    if ((int)blockIdx.x >= *ntile) return;
    int2 tl = tiles[blockIdx.x];
    int e = tl.x, pbase = tl.y;
    int m = min(16, eoff[e+1] - pbase);
    __shared__ float4 xs[16][128];
    __shared__ int tok_s[16];
    int tid = threadIdx.x;
    if (tid < 16) tok_s[tid] = ep_tok[pbase + ((tid < m) ? tid : 0)];
    __syncthreads();
    const float4* x4 = (const float4*)x;
    for (int q = tid; q < 16*128; q += 256) {
        int i = q >> 7, k = q & 127;
        xs[i][k] = x4[(size_t)tok_s[i] * 128 + k];
    }
    __syncthreads();
    int c = blockIdx.y * 256 + tid;             // 0..1023
    const float4* wr = (const float4*)(w1 + ((size_t)e * EDIM + c) * DIMM);
    float acc[16];
    #pragma unroll
    for (int i = 0; i < 16; ++i) acc[i] = 0.f;
    for (int kk = 0; kk < 128; ++kk) {
        float4 wv = wr[kk];
        #pragma unroll
        for (int i = 0; i < 16; ++i) acc[i] += dot4(wv, xs[i][kk]);
    }
    float bb = b1[(size_t)e * EDIM + c];
    for (int i = 0; i < m; ++i)
        hbuf[(size_t)(pbase + i) * EDIM + c] = gelu_exact(acc[i] + bb);
}

// ---------------- expert FFN2: eo += pw * (H @ W2^T + b2) ----------------
__global__ __launch_bounds__(256) void k_effn2(
    const float* __restrict__ hbuf, const float* __restrict__ w2, const float* __restrict__ b2,
    const int2* __restrict__ tiles, const int* __restrict__ ntile,
    const int* __restrict__ eoff, const int* __restrict__ ep_tok, const float* __restrict__ ep_w,
    float* __restrict__ eo) {
    if ((int)blockIdx.x >= *ntile) return;
    int2 tl = tiles[blockIdx.x];
    int e = tl.x, pbase = tl.y;
    int m = min(16, eoff[e+1] - pbase);
    int kc = blockIdx.z;                         // k-half of 1024
    __shared__ float4 hs[16][128];
    __shared__ int tok_s[16];
    __shared__ float pw_s[16];
    int tid = threadIdx.x;
    if (tid < 16) {
        int ok = tid < m;
        tok_s[tid] = ok ? ep_tok[pbase + tid] : 0;
        pw_s[tid]  = ok ? ep_w[pbase + tid] : 0.f;
    }
    __syncthreads();
    const float4* h4 = (const float4*)hbuf;
    for (int q = tid; q < 16*128; q += 256) {
        int i = q >> 7, k = q & 127;
        hs[i][k] = h4[(size_t)(pbase + ((i < m) ? i : 0)) * 256 + kc * 128 + k];
    }
    __syncthreads();
    int c = blockIdx.y * 256 + tid;              // 0..511
    const float4* wr = (const float4*)(w2 + ((size_t)e * DIMM + c) * EDIM + (size_t)kc * 512);
    float acc[16];
    #pragma unroll
    for (int i = 0; i < 16; ++i) acc[i] = 0.f;
    for (int kk = 0; kk < 128; ++kk) {
        float4 wv = wr[kk];
        #pragma unroll
        for (int i = 0; i < 16; ++i) acc[i] += dot4(wv, hs[i][kk]);
    }
    float bb = (kc == 0) ? b2[(size_t)e * DIMM + c] : 0.f;
    for (int i = 0; i < m; ++i) {
        float val = (acc[i] + bb) * pw_s[i];
        atomicAdd(&eo[(size_t)tok_s[i] * DIMM + c], val);
    }
}

// ---------------- micro router logits: mlog = eo @ mrw^T + mrb ----------------
__global__ __launch_bounds__(256) void k_mlog(
    const float* __restrict__ eo, const float* __restrict__ mw, const float* __restrict__ mb,
    float* __restrict__ mlog) {
    int t0 = blockIdx.x * 8;
    __shared__ float4 es[8][128];
    int tid = threadIdx.x;
    const float4* eo4 = (const float4*)eo;
    for (int q = tid; q < 8*128; q += 256) {
        int i = q >> 7, k = q & 127;
        es[i][k] = eo4[(size_t)(t0 + i) * 128 + k];
    }
    __syncthreads();
    {
        int n = tid;
        const float4* wr = (const float4*)(mw + (size_t)n * DIMM);
        float acc[8];
        #pragma unroll
        for (int i = 0; i < 8; ++i) acc[i] = 0.f;
        for (int kk = 0; kk < 128; ++kk) {
            float4 wv = wr[kk];
            #pragma unroll
            for (int i = 0; i < 8; ++i) acc[i] += dot4(wv, es[i][kk]);
        }
        float bb = mb[n];
        for (int i = 0; i < 8; ++i) mlog[(size_t)(t0 + i) * NMIC + n] = acc[i] + bb;
    }
    if (tid < NMIC - 256) {
        int n = 256 + tid;
        const float4* wr = (const float4*)(mw + (size_t)n * DIMM);
        float acc[8];
        #pragma unroll
        for (int i = 0; i < 8; ++i) acc[i] = 0.f;
        for (int kk = 0; kk < 128; ++kk) {
            float4 wv = wr[kk];
            #pragma unroll
            for (int i = 0; i < 8; ++i) acc[i] += dot4(wv, es[i][kk]);
        }
        float bb = mb[n];
        for (int i = 0; i < 8; ++i) mlog[(size_t)(t0 + i) * NMIC + n] = acc[i] + bb;
    }
}

// ---------------- micro top-8 softmax + renorm ----------------
__global__ void k_mtop(const float* __restrict__ mlog, int* __restrict__ mtopi,
                       float* __restrict__ mtopp, int* __restrict__ mcnt) {
    int wave = threadIdx.x >> 6, lane = threadIdx.x & 63;
    int t = blockIdx.x * 4 + wave;
    if (t >= T_TOK) return;
    float v[6]; int vi[6];
    #pragma unroll
    for (int j = 0; j < 6; ++j) {
        int n = lane + 64*j;
        vi[j] = n;
        v[j] = (n < NMIC) ? mlog[(size_t)t * NMIC + n] : -1e30f;
    }
    float M = v[0];
    #pragma unroll
    for (int j = 1; j < 6; ++j) M = fmaxf(M, v[j]);
    #pragma unroll
    for (int o = 32; o; o >>= 1) M = fmaxf(M, __shfl_xor(M, o));
    float Z = 0.f;
    #pragma unroll
    for (int j = 0; j < 6; ++j) Z += expf(v[j] - M);
    Z = wave_sum(Z);
    float bk[8]; int bi[8];
    for (int k = 0; k < 8; ++k) {
        float lv = v[0]; int li = vi[0];
        #pragma unroll
        for (int j = 1; j < 6; ++j)
            if (v[j] > lv) { lv = v[j]; li = vi[j]; }
        #pragma unroll
        for (int o = 32; o; o >>= 1) {
            float ov = __shfl_xor(lv, o); int oi = __shfl_xor(li, o);
            if (ov > lv || (ov == lv && oi < li)) { lv = ov; li = oi; }
        }
        bk[k] = expf(lv - M) / Z; bi[k] = li;
        #pragma unroll
        for (int j = 0; j < 6; ++j) if (vi[j] == li) v[j] = -1e30f;
    }
    float s = 0.f;
    #pragma unroll
    for (int k = 0; k < 8; ++k) s += bk[k];
    s += 1e-8f;
    if (lane == 0) {
        for (int k = 0; k < 8; ++k) {
            mtopi[t*8 + k] = bi[k];
            mtopp[t*8 + k] = bk[k] / s;
            atomicAdd(&mcnt[bi[k]], 1);
        }
    }
}

// ---------------- micro FFN (fused): hm=gelu(EO@W1^T+b1); r=EO+HM@W2^T+b2; LN; mo += p*n ----
__global__ __launch_bounds__(256) void k_micro(
    const float* __restrict__ eo, const float* __restrict__ w1, const float* __restrict__ b1,
    const float* __restrict__ w2, const float* __restrict__ b2,
    const float* __restrict__ g, const float* __restrict__ beta,
    const int2* __restrict__ tiles, const int* __restrict__ ntile,
    const int* __restrict__ moff, const int* __restrict__ mp_tok, const float* __restrict__ mp_w,
    float* __restrict__ mo) {
    if ((int)blockIdx.x >= *ntile) return;
    int2 tl = tiles[blockIdx.x];
    int mi = tl.x, pbase = tl.y;
    int pm = min(16, moff[mi+1] - pbase);
    __shared__ float4 es[16][128];   // eo rows, becomes residual r
    __shared__ float4 hs[16][64];    // hidden
    __shared__ int tok_s[16];
    __shared__ float pw_s[16];
    int tid = threadIdx.x;
    if (tid < 16) {
        int ok = tid < pm;
        tok_s[tid] = mp_tok[pbase + (ok ? tid : 0)];
        pw_s[tid]  = ok ? mp_w[pbase + tid] : 0.f;
    }
    __syncthreads();
    const float4* eo4 = (const float4*)eo;
    for (int q = tid; q < 16*128; q += 256) {
        int i = q >> 7, k = q & 127;
        es[i][k] = eo4[(size_t)tok_s[i] * 128 + k];
    }
    __syncthreads();
    // phase A: hidden (n = tid in 0..255)
    {
        const float4* wr = (const float4*)(w1 + ((size_t)mi * HIDD + tid) * DIMM);
        float acc[16];
        #pragma unroll
        for (int i = 0; i < 16; ++i) acc[i] = 0.f;
        for (int kk = 0; kk < 128; ++kk) {
            float4 wv = wr[kk];
            #pragma unroll
            for (int i = 0; i < 16; ++i) acc[i] += dot4(wv, es[i][kk]);
        }
        float bb = b1[(size_t)mi * HIDD + tid];
        float* hsf = (float*)hs;
        #pragma unroll
        for (int i = 0; i < 16; ++i) hsf[i*256 + tid] = gelu_exact(acc[i] + bb);
    }
    __syncthreads();
    // phase B: r = eo + ym, in place in es
    float* esf = (float*)es;
    for (int dc = 0; dc < 2; ++dc) {
        int d = dc*256 + tid;
        const float4* wr = (const float4*)(w2 + ((size_t)mi * DIMM + d) * HIDD);
        float acc[16];
        #pragma unroll
        for (int i = 0; i < 16; ++i) acc[i] = 0.f;
        for (int kk = 0; kk < 64; ++kk) {
            float4 wv = wr[kk];
            #pragma unroll
            for (int i = 0; i < 16; ++i) acc[i] += dot4(wv, hs[i][kk]);
        }
        float bb = b2[(size_t)mi * DIMM + d];
        #pragma unroll
        for (int i = 0; i < 16; ++i) esf[i*512 + d] += acc[i] + bb;
    }
    __syncthreads();
    // LayerNorm per pair + weighted accumulate into mo
    int wave = tid >> 6, lane = tid & 63;
    for (int i = wave; i < pm; i += 4) {
        float vv[8];
        float sum = 0.f;
        #pragma unroll
        for (int j = 0; j < 8; ++j) { vv[j] = esf[i*512 + lane + 64*j]; sum += vv[j]; }
        sum = wave_sum(sum);
        float mu = sum * (1.f/512.f);
        float var = 0.f;
        #pragma unroll
        for (int j = 0; j < 8; ++j) { float d0 = vv[j] - mu; var += d0*d0; }
        var = wave_sum(var) * (1.f/512.f);
        float rstd = rsqrtf(var + 1e-5f);
        float p = pw_s[i]; int t = tok_s[i];
        #pragma unroll
        for (int j = 0; j < 8; ++j) {
            int d = lane + 64*j;
            float nj = (vv[j] - mu) * rstd * g[(size_t)mi * DIMM + d] + beta[(size_t)mi * DIMM + d];
            atomicAdd(&mo[(size_t)t * DIMM + d], p * nj);
        }
    }
}

// ---------------- final LN over eo + 0.1*mo ----------------
__global__ void k_final(const float* __restrict__ eo, const float* __restrict__ mo,
                        const float* __restrict__ g, const float* __restrict__ b,
                        float* __restrict__ out) {
    int wave = threadIdx.x >> 6, lane = threadIdx.x & 63;
    int t = blockIdx.x * 4 + wave;
    if (t >= T_TOK) return;
    float vv[8];
    float sum = 0.f;
    #pragma unroll
    for (int j = 0; j < 8; ++j) {
        int d = lane + 64*j;
        vv[j] = eo[(size_t)t * DIMM + d] + 0.1f * mo[(size_t)t * DIMM + d];
        sum += vv[j];
    }
    sum = wave_sum(sum);
    float mu = sum * (1.f/512.f);
    float var = 0.f;
    #pragma unroll
    for (int j = 0; j < 8; ++j) { float d0 = vv[j] - mu; var += d0*d0; }
    var = wave_sum(var) * (1.f/512.f);
    float rstd = rsqrtf(var + 1e-5f);
    #pragma unroll
    for (int j = 0; j < 8; ++j) {
        int d = lane + 64*j;
        out[(size_t)t * DIMM + d] = (vv[j] - mu) * rstd * g[d] + b[d];
    }
}

extern "C" void kernel_launch(void* const* d_in, const int* in_sizes, int n_in,
                              void* d_out, int out_size, void* d_ws, size_t ws_size,
                              hipStream_t stream) {
    const float* x    = (const float*)d_in[0];
    const float* rw   = (const float*)d_in[1];
    const float* rb   = (const float*)d_in[2];
    const float* ew1  = (const float*)d_in[3];
    const float* eb1  = (const float*)d_in[4];
    const float* ew2  = (const float*)d_in[5];
    const float* eb2  = (const float*)d_in[6];
    const float* mrw  = (const float*)d_in[7];
    const float* mrb  = (const float*)d_in[8];
    const float* mw1  = (const float*)d_in[9];
    const float* mb1  = (const float*)d_in[10];
    const float* mw2  = (const float*)d_in[11];
    const float* mb2  = (const float*)d_in[12];
    const float* mg   = (const float*)d_in[13];
    const float* mbeta= (const float*)d_in[14];
    const float* ng   = (const float*)d_in[15];
    const float* nb   = (const float*)d_in[16];
    float* out = (float*)d_out;

    char* w = (char*)d_ws;
    auto alloc = [&](size_t bytes) -> char* {
        char* p = w;
        w += (bytes + 255) & ~(size_t)255;
        return p;
    };
    float* eo    = (float*)alloc((size_t)T_TOK * DIMM * 4);   // 2 MB
    float* mo    = (float*)alloc((size_t)T_TOK * DIMM * 4);   // 2 MB (contiguous with eo)
    float* hbuf  = (float*)alloc((size_t)2048 * EDIM * 4);    // 8 MB
    float* mlog  = (float*)alloc((size_t)T_TOK * NMIC * 4);   // 1.3 MB
    float* ewts  = (float*)alloc(2048 * 4);
    float* mtopp = (float*)alloc(8192 * 4);
    float* ep_w  = (float*)alloc(2048 * 4);
    float* mp_w  = (float*)alloc(8192 * 4);
    int*   eidx  = (int*)alloc(2048 * 4);
    int*   mtopi = (int*)alloc(8192 * 4);
    int*   cnts  = (int*)alloc((NEXP + NMIC) * 4);            // ecnt | mcnt contiguous
    int*   ecnt  = cnts;
    int*   mcnt  = cnts + NEXP;
    int*   eoff  = (int*)alloc((NEXP + 1) * 4);
    int*   ecur  = (int*)alloc(NEXP * 4);
    int*   moff  = (int*)alloc((NMIC + 1) * 4);
    int*   mcur  = (int*)alloc(NMIC * 4);
    int2*  etile = (int2*)alloc(ETILES * 8);
    int2*  mtile = (int2*)alloc(MTILES * 8);
    int*   entile= (int*)alloc(4);
    int*   mntile= (int*)alloc(4);
    int*   ep_tok= (int*)alloc(2048 * 4);
    int*   mp_tok= (int*)alloc(8192 * 4);

    hipMemsetAsync(eo, 0, (size_t)2 * T_TOK * DIMM * 4, stream);   // eo + mo
    hipMemsetAsync(cnts, 0, (NEXP + NMIC) * 4, stream);

    k_router <<<T_TOK/4, 256, 0, stream>>>(x, rw, rb, eidx, ewts, ecnt);
    k_scan   <<<1, 512, 0, stream>>>(ecnt, NEXP, 16, eoff, ecur, etile, entile);
    k_scatter<<<(T_TOK*2 + 255)/256, 256, 0, stream>>>(eidx, ewts, T_TOK*2, 2, ecur, ep_tok, ep_w);
    k_effn1  <<<dim3(ETILES, 4, 1), 256, 0, stream>>>(x, ew1, eb1, etile, entile, eoff, ep_tok, hbuf);
    k_effn2  <<<dim3(ETILES, 2, 2), 256, 0, stream>>>(hbuf, ew2, eb2, etile, entile, eoff, ep_tok, ep_w, eo);
    k_mlog   <<<T_TOK/8, 256, 0, stream>>>(eo, mrw, mrb, mlog);
    k_mtop   <<<T_TOK/4, 256, 0, stream>>>(mlog, mtopi, mtopp, mcnt);
    k_scan   <<<1, 512, 0, stream>>>(mcnt, NMIC, 16, moff, mcur, mtile, mntile);
    k_scatter<<<(T_TOK*8 + 255)/256, 256, 0, stream>>>(mtopi, mtopp, T_TOK*8, 8, mcur, mp_tok, mp_w);
    k_micro  <<<MTILES, 256, 0, stream>>>(eo, mw1, mb1, mw2, mb2, mg, mbeta,
                                          mtile, mntile, moff, mp_tok, mp_w, mo);
    k_final  <<<T_TOK/4, 256, 0, stream>>>(eo, mo, ng, nb, out);
}

// Round 2
// 719.369 us; speedup vs baseline: 1.1893x; 1.1893x over previous
//
#include <hip/hip_runtime.h>
#include <hip/hip_bf16.h>
#include <math.h>

#define T_TOK 1024
#define DIMM  512      // model dim
#define EDIM  1024     // expert hidden
#define HIDD  256      // micro hidden
#define NEXP  8
#define NMIC  325
#define E8TILES 264    // max expert tiles (8-pair)
#define MTILES  840    // max micro tiles (16-pair)

typedef __attribute__((ext_vector_type(8))) short bf16x8;   // 8 bf16 (4 VGPRs)
typedef __attribute__((ext_vector_type(4))) float f32x4;    // 4 fp32 acc

__device__ __forceinline__ float dot4(float4 a, float4 b) {
    return a.x*b.x + a.y*b.y + a.z*b.z + a.w*b.w;
}
__device__ __forceinline__ float gelu_exact(float x) {
    return 0.5f * x * (1.0f + erff(x * 0.70710678118654752f));
}
__device__ __forceinline__ float wave_sum(float v) {
    #pragma unroll
    for (int o = 32; o; o >>= 1) v += __shfl_xor(v, o);
    return v;
}
__device__ __forceinline__ short f2bf(float f) {
    union { __hip_bfloat16 h; short s; } u;
    u.h = __float2bfloat16(f);
    return u.s;
}
__device__ __forceinline__ bf16x8 cvt8(float4 a, float4 b) {
    bf16x8 r;
    r[0]=f2bf(a.x); r[1]=f2bf(a.y); r[2]=f2bf(a.z); r[3]=f2bf(a.w);
    r[4]=f2bf(b.x); r[5]=f2bf(b.y); r[6]=f2bf(b.z); r[7]=f2bf(b.w);
    return r;
}

// ---------------- expert router: softmax over 8, top-2, renorm ----------------
__global__ void k_router(const float* __restrict__ x, const float* __restrict__ rw,
                         const float* __restrict__ rb, int* __restrict__ eidx,
                         float* __restrict__ ew, int* __restrict__ ecnt) {
    int wave = threadIdx.x >> 6, lane = threadIdx.x & 63;
    int t = blockIdx.x * 4 + wave;
    if (t >= T_TOK) return;
    const float* xr = x + (size_t)t * DIMM;
    float xv[8];
    #pragma unroll
    for (int j = 0; j < 8; ++j) xv[j] = xr[lane + 64*j];
    float p[NEXP];
    #pragma unroll
    for (int e = 0; e < NEXP; ++e) {
        const float* wr = rw + (size_t)e * DIMM;
        float a = 0.f;
        #pragma unroll
        for (int j = 0; j < 8; ++j) a += xv[j] * wr[lane + 64*j];
        p[e] = wave_sum(a) + rb[e];
    }
    float m = p[0];
    #pragma unroll
    for (int e = 1; e < NEXP; ++e) m = fmaxf(m, p[e]);
    float Z = 0.f;
    #pragma unroll
    for (int e = 0; e < NEXP; ++e) { p[e] = expf(p[e] - m); Z += p[e]; }
    #pragma unroll
    for (int e = 0; e < NEXP; ++e) p[e] /= Z;
    int i1 = 0; float v1 = p[0];
    #pragma unroll
    for (int e = 1; e < NEXP; ++e) if (p[e] > v1) { v1 = p[e]; i1 = e; }
    int i2 = -1; float v2 = -1.f;
    #pragma unroll
    for (int e = 0; e < NEXP; ++e) if (e != i1 && p[e] > v2) { v2 = p[e]; i2 = e; }
    float s = v1 + v2 + 1e-8f;
    if (lane == 0) {
        eidx[t*2] = i1; eidx[t*2+1] = i2;
        ew[t*2] = v1 / s; ew[t*2+1] = v2 / s;
        atomicAdd(&ecnt[i1], 1); atomicAdd(&ecnt[i2], 1);
    }
}

// ---------------- generic scan + tile builder (1 block, 512 threads) ----------------
__global__ void k_scan(const int* __restrict__ cnt, int n, int pm,
                       int* __restrict__ off, int* __restrict__ cur,
                       int2* __restrict__ tiles, int* __restrict__ ntile) {
    __shared__ int s[512], s2[512];
    int tid = threadIdx.x;
    int v  = (tid < n) ? cnt[tid] : 0;
    int tc = (v + pm - 1) / pm;
    s[tid] = v; s2[tid] = tc;
    __syncthreads();
    for (int d = 1; d < 512; d <<= 1) {
        int a = (tid >= d) ? s[tid-d] : 0;
        int b = (tid >= d) ? s2[tid-d] : 0;
        __syncthreads();
        s[tid] += a; s2[tid] += b;
        __syncthreads();
    }
    int myoff = s[tid] - v, tb = s2[tid] - tc;
    if (tid < n) { off[tid] = myoff; cur[tid] = myoff; }
    if (tid == n-1) off[n] = s[tid];
    if (tid == 511) *ntile = s2[511];
    for (int j = 0; j < tc; ++j) tiles[tb + j] = make_int2(tid, myoff + j*pm);
}

// ---------------- generic scatter ----------------
__global__ void k_scatter(const int* __restrict__ idx, const float* __restrict__ w,
                          int total, int S, int* __restrict__ cur,
                          int* __restrict__ ptok, float* __restrict__ pw) {
    int g = blockIdx.x * blockDim.x + threadIdx.x;
    if (g >= total) return;
    int t = g / S;
    int e = idx[g];
    int pos = atomicAdd(&cur[e], 1);
    ptok[pos] = t; pw[pos] = w[g];
}

// ---------------- expert FFN1 (fp32, 8-pair tiles): h = gelu(X @ W1^T + b1) ----------
__global__ __launch_bounds__(256) void k_effn1(
    const float* __restrict__ x, const float* __restrict__ w1, const float* __restrict__ b1,
    const int2* __restrict__ tiles, const int* __restrict__ ntile,
    const int* __restrict__ eoff, const int* __restrict__ ep_tok,
    float* __restrict__ hbuf) {
    if ((int)blockIdx.x >= *ntile) return;
    int2 tl = tiles[blockIdx.x];
    int e = tl.x, pbase = tl.y;
    int m = min(8, eoff[e+1] - pbase);
    __shared__ float4 xs[8][128];
    __shared__ int tok_s[8];
    int tid = threadIdx.x;
    if (tid < 8) tok_s[tid] = ep_tok[pbase + ((tid < m) ? tid : 0)];
    __syncthreads();
    const float4* x4 = (const float4*)x;
    for (int q = tid; q < 8*128; q += 256) {
        int i = q >> 7, k = q & 127;
        xs[i][k] = x4[(size_t)tok_s[i] * 128 + k];
    }
    __syncthreads();
    int c = blockIdx.y * 256 + tid;             // 0..1023
    const float4* wr = (const float4*)(w1 + ((size_t)e * EDIM + c) * DIMM);
    float acc[8];
    #pragma unroll
    for (int i = 0; i < 8; ++i) acc[i] = 0.f;
    for (int kk = 0; kk < 128; ++kk) {
        float4 wv = wr[kk];
        #pragma unroll
        for (int i = 0; i < 8; ++i) acc[i] += dot4(wv, xs[i][kk]);
    }
    float bb = b1[(size_t)e * EDIM + c];
    for (int i = 0; i < m; ++i)
        hbuf[(size_t)(pbase + i) * EDIM + c] = gelu_exact(acc[i] + bb);
}

// ---------------- expert FFN2 (fp32, 8-pair tiles): eo += pw * (H @ W2^T + b2) --------
__global__ __launch_bounds__(256) void k_effn2(
    const float* __restrict__ hbuf, const float* __restrict__ w2, const float* __restrict__ b2,
    const int2* __restrict__ tiles, const int* __restrict__ ntile,
    const int* __restrict__ eoff, const int* __restrict__ ep_tok, const float* __restrict__ ep_w,
    float* __restrict__ eo) {
    if ((int)blockIdx.x >= *ntile) return;
    int2 tl = tiles[blockIdx.x];
    int e = tl.x, pbase = tl.y;
    int m = min(8, eoff[e+1] - pbase);
    int kc = blockIdx.z;                         // k-half of 1024
    __shared__ float4 hs[8][128];
    __shared__ int tok_s[8];
    __shared__ float pw_s[8];
    int tid = threadIdx.x;
    if (tid < 8) {
        int ok = tid < m;
        tok_s[tid] = ok ? ep_tok[pbase + tid] : 0;
        pw_s[tid]  = ok ? ep_w[pbase + tid] : 0.f;
    }
    __syncthreads();
    const float4* h4 = (const float4*)hbuf;
    for (int q = tid; q < 8*128; q += 256) {
        int i = q >> 7, k = q & 127;
        hs[i][k] = h4[(size_t)(pbase + ((i < m) ? i : 0)) * 256 + kc * 128 + k];
    }
    __syncthreads();
    int c = blockIdx.y * 256 + tid;              // 0..511
    const float4* wr = (const float4*)(w2 + ((size_t)e * DIMM + c) * EDIM + (size_t)kc * 512);
    float acc[8];
    #pragma unroll
    for (int i = 0; i < 8; ++i) acc[i] = 0.f;
    for (int kk = 0; kk < 128; ++kk) {
        float4 wv = wr[kk];
        #pragma unroll
        for (int i = 0; i < 8; ++i) acc[i] += dot4(wv, hs[i][kk]);
    }
    float bb = (kc == 0) ? b2[(size_t)e * DIMM + c] : 0.f;
    for (int i = 0; i < m; ++i) {
        float val = (acc[i] + bb) * pw_s[i];
        atomicAdd(&eo[(size_t)tok_s[i] * DIMM + c], val);
    }
}

// ---------------- micro router logits: mlog = eo @ mrw^T + mrb (4 tokens/block) -------
__global__ __launch_bounds__(384) void k_mlog(
    const float* __restrict__ eo, const float* __restrict__ mw, const float* __restrict__ mb,
    float* __restrict__ mlog) {
    int t0 = blockIdx.x * 4;
    __shared__ float4 es[4][128];
    int tid = threadIdx.x;
    const float4* eo4 = (const float4*)eo;
    for (int q = tid; q < 4*128; q += 384) {
        int i = q >> 7, k = q & 127;
        es[i][k] = eo4[(size_t)(t0 + i) * 128 + k];
    }
    __syncthreads();
    if (tid < NMIC) {
        const float4* wr = (const float4*)(mw + (size_t)tid * DIMM);
        float acc[4] = {0.f, 0.f, 0.f, 0.f};
        for (int kk = 0; kk < 128; ++kk) {
            float4 wv = wr[kk];
            #pragma unroll
            for (int i = 0; i < 4; ++i) acc[i] += dot4(wv, es[i][kk]);
        }
        float bb = mb[tid];
        #pragma unroll
        for (int i = 0; i < 4; ++i) mlog[(size_t)(t0 + i) * NMIC + tid] = acc[i] + bb;
    }
}

// ---------------- micro top-8 softmax + renorm ----------------
__global__ void k_mtop(const float* __restrict__ mlog, int* __restrict__ mtopi,
                       float* __restrict__ mtopp, int* __restrict__ mcnt) {
    int wave = threadIdx.x >> 6, lane = threadIdx.x & 63;
    int t = blockIdx.x * 4 + wave;
    if (t >= T_TOK) return;
    float v[6]; int vi[6];
    #pragma unroll
    for (int j = 0; j < 6; ++j) {
        int n = lane + 64*j;
        vi[j] = n;
        v[j] = (n < NMIC) ? mlog[(size_t)t * NMIC + n] : -1e30f;
    }
    float M = v[0];
    #pragma unroll
    for (int j = 1; j < 6; ++j) M = fmaxf(M, v[j]);
    #pragma unroll
    for (int o = 32; o; o >>= 1) M = fmaxf(M, __shfl_xor(M, o));
    float Z = 0.f;
    #pragma unroll
    for (int j = 0; j < 6; ++j) Z += expf(v[j] - M);
    Z = wave_sum(Z);
    float bk[8]; int bi[8];
    for (int k = 0; k < 8; ++k) {
        float lv = v[0]; int li = vi[0];
        #pragma unroll
        for (int j = 1; j < 6; ++j)
            if (v[j] > lv) { lv = v[j]; li = vi[j]; }
        #pragma unroll
        for (int o = 32; o; o >>= 1) {
            float ov = __shfl_xor(lv, o); int oi = __shfl_xor(li, o);
            if (ov > lv || (ov == lv && oi < li)) { lv = ov; li = oi; }
        }
        bk[k] = expf(lv - M) / Z; bi[k] = li;
        #pragma unroll
        for (int j = 0; j < 6; ++j) if (vi[j] == li) v[j] = -1e30f;
    }
    float s = 0.f;
    #pragma unroll
    for (int k = 0; k < 8; ++k) s += bk[k];
    s += 1e-8f;
    if (lane == 0) {
        for (int k = 0; k < 8; ++k) {
            mtopi[t*8 + k] = bi[k];
            mtopp[t*8 + k] = bk[k] / s;
            atomicAdd(&mcnt[bi[k]], 1);
        }
    }
}

// ---------------- micro FFN, bf16 MFMA 16x16x32 ----------------
// A-fragment order for (m,k): off = (k>>5)*512 + (((k>>3)&3)*16 + m)*8 + (k&7)
// C/D layout: col = lane&15, row = (lane>>4)*4 + reg   [m89/m91 verified]
__global__ __launch_bounds__(256, 4) void k_micro(
    const float* __restrict__ eo, const float* __restrict__ w1, const float* __restrict__ b1,
    const float* __restrict__ w2, const float* __restrict__ b2,
    const float* __restrict__ g, const float* __restrict__ beta,
    const int2* __restrict__ tiles, const int* __restrict__ ntile,
    const int* __restrict__ moff, const int* __restrict__ mp_tok, const float* __restrict__ mp_w,
    float* __restrict__ mo) {
    if ((int)blockIdx.x >= *ntile) return;
    int2 tl = tiles[blockIdx.x];
    int mi = tl.x, pbase = tl.y;
    int pm = min(16, moff[mi+1] - pbase);
    // LDS: hf bf16[4096] at 0 (8KB); eof bf16[8192] at 8192 (16KB); R fp32[16][520] at 0 (33.3KB)
    __shared__ __align__(16) char smem[34816];
    short* hf  = (short*)smem;
    short* eof = (short*)(smem + 8192);
    float* R   = (float*)smem;
    __shared__ int tok_s[16];
    __shared__ float pw_s[16];
    int tid = threadIdx.x;
    if (tid < 16) {
        int ok = tid < pm;
        tok_s[tid] = mp_tok[pbase + (ok ? tid : 0)];
        pw_s[tid]  = ok ? mp_w[pbase + tid] : 0.f;
    }
    __syncthreads();
    // ---- stage EO tile -> bf16 A-fragment order ----
    int m0 = tid & 15;
    const float4* eorow = (const float4*)(eo + (size_t)tok_s[m0] * DIMM);
    for (int kk = tid >> 4; kk < 128; kk += 16) {      // kk = k/4
        float4 v = eorow[kk];
        int off = ((kk >> 3) * 512) + ((((kk >> 1) & 3) * 16 + m0) * 8) + ((kk & 1) * 4);
        short4 s4; s4.x = f2bf(v.x); s4.y = f2bf(v.y); s4.z = f2bf(v.z); s4.w = f2bf(v.w);
        *(short4*)(eof + off) = s4;
    }
    __syncthreads();
    int wave = tid >> 6, lane = tid & 63;
    int quad = lane >> 4, lcol = lane & 15;
    f32x4 zero = {0.f, 0.f, 0.f, 0.f};
    // ---- phase A: H[16x256] = EO @ W1^T ----
    f32x4 accA[4];
    #pragma unroll
    for (int q = 0; q < 4; ++q) accA[q] = zero;
    const float* w1base = w1 + (size_t)mi * HIDD * DIMM;
    for (int ks = 0; ks < 16; ++ks) {
        bf16x8 a = *(bf16x8*)(eof + ks*512 + lane*8);
        int kb = ks*32 + quad*8;
        #pragma unroll
        for (int q = 0; q < 4; ++q) {
            int n = wave*64 + q*16 + lcol;
            const float* wp = w1base + (size_t)n * DIMM + kb;
            float4 wa = *(const float4*)wp;
            float4 wb = *(const float4*)(wp + 4);
            accA[q] = __builtin_amdgcn_mfma_f32_16x16x32_bf16(a, cvt8(wa, wb), accA[q], 0, 0, 0);
        }
    }
    // ---- gelu + bias, write H to hf in A-fragment order (hf disjoint from eof) ----
    #pragma unroll
    for (int q = 0; q < 4; ++q) {
        int h = wave*64 + q*16 + lcol;
        float bb = b1[(size_t)mi * HIDD + h];
        int obase = ((h >> 5) * 512) + (((h >> 3) & 3) * 16) * 8 + (h & 7);
        #pragma unroll
        for (int r = 0; r < 4; ++r) {
            int mm = quad*4 + r;
            hf[obase + mm*8] = f2bf(gelu_exact(accA[q][r] + bb));
        }
    }
    __syncthreads();
    // ---- phase B: Y[16x512] = H @ W2^T ----
    f32x4 accB[8];
    #pragma unroll
    for (int q = 0; q < 8; ++q) accB[q] = zero;
    const float* w2base = w2 + (size_t)mi * DIMM * HIDD;
    for (int ks = 0; ks < 8; ++ks) {
        bf16x8 a = *(bf16x8*)(hf + ks*512 + lane*8);
        int kb = ks*32 + quad*8;
        #pragma unroll
        for (int q = 0; q < 8; ++q) {
            int d = wave*128 + q*16 + lcol;
            const float* wp = w2base + (size_t)d * HIDD + kb;
            float4 wa = *(const float4*)wp;
            float4 wb = *(const float4*)(wp + 4);
            accB[q] = __builtin_amdgcn_mfma_f32_16x16x32_bf16(a, cvt8(wa, wb), accB[q], 0, 0, 0);
        }
    }
    __syncthreads();   // all hf reads done before R overwrites [0, 33.3KB)
    // ---- write R = Y + b2 (stride 520 breaks bank conflicts) ----
    #pragma unroll
    for (int q = 0; q < 8; ++q) {
        int d = wave*128 + q*16 + lcol;
        float bb = b2[(size_t)mi * DIMM + d];
        #pragma unroll
        for (int r = 0; r < 4; ++r) {
            int mm = quad*4 + r;
            R[mm*520 + d] = accB[q][r] + bb;
        }
    }
    __syncthreads();
    // ---- per-pair LayerNorm of (eo + Y), weighted accumulate into mo ----
    for (int i = wave; i < pm; i += 4) {
        int t = tok_s[i];
        const float* eort = eo + (size_t)t * DIMM;
        float vv[8];
        float sum = 0.f;
        #pragma unroll
        for (int j = 0; j < 8; ++j) {
            int d = lane + 64*j;
            vv[j] = R[i*520 + d] + eort[d];
            sum += vv[j];
        }
        sum = wave_sum(sum);
        float mu = sum * (1.f/512.f);
        float var = 0.f;
        #pragma unroll
        for (int j = 0; j < 8; ++j) { float d0 = vv[j] - mu; var += d0*d0; }
        var = wave_sum(var) * (1.f/512.f);
        float rstd = rsqrtf(var + 1e-5f);
        float p = pw_s[i];
        #pragma unroll
        for (int j = 0; j < 8; ++j) {
            int d = lane + 64*j;
            float nj = (vv[j] - mu) * rstd * g[(size_t)mi * DIMM + d] + beta[(size_t)mi * DIMM + d];
            atomicAdd(&mo[(size_t)t * DIMM + d], p * nj);
        }
    }
}

// ---------------- final LN over eo + 0.1*mo ----------------
__global__ void k_final(const float* __restrict__ eo, const float* __restrict__ mo,
                        const float* __restrict__ g, const float* __restrict__ b,
                        float* __restrict__ out) {
    int wave = threadIdx.x >> 6, lane = threadIdx.x & 63;
    int t = blockIdx.x * 4 + wave;
    if (t >= T_TOK) return;
    float vv[8];
    float sum = 0.f;
    #pragma unroll
    for (int j = 0; j < 8; ++j) {
        int d = lane + 64*j;
        vv[j] = eo[(size_t)t * DIMM + d] + 0.1f * mo[(size_t)t * DIMM + d];
        sum += vv[j];
    }
    sum = wave_sum(sum);
    float mu = sum * (1.f/512.f);
    float var = 0.f;
    #pragma unroll
    for (int j = 0; j < 8; ++j) { float d0 = vv[j] - mu; var += d0*d0; }
    var = wave_sum(var) * (1.f/512.f);
    float rstd = rsqrtf(var + 1e-5f);
    #pragma unroll
    for (int j = 0; j < 8; ++j) {
        int d = lane + 64*j;
        out[(size_t)t * DIMM + d] = (vv[j] - mu) * rstd * g[d] + b[d];
    }
}

extern "C" void kernel_launch(void* const* d_in, const int* in_sizes, int n_in,
                              void* d_out, int out_size, void* d_ws, size_t ws_size,
                              hipStream_t stream) {
    const float* x    = (const float*)d_in[0];
    const float* rw   = (const float*)d_in[1];
    const float* rb   = (const float*)d_in[2];
    const float* ew1  = (const float*)d_in[3];
    const float* eb1  = (const float*)d_in[4];
    const float* ew2  = (const float*)d_in[5];
    const float* eb2  = (const float*)d_in[6];
    const float* mrw  = (const float*)d_in[7];
    const float* mrb  = (const float*)d_in[8];
    const float* mw1  = (const float*)d_in[9];
    const float* mb1  = (const float*)d_in[10];
    const float* mw2  = (const float*)d_in[11];
    const float* mb2  = (const float*)d_in[12];
    const float* mg   = (const float*)d_in[13];
    const float* mbeta= (const float*)d_in[14];
    const float* ng   = (const float*)d_in[15];
    const float* nb   = (const float*)d_in[16];
    float* out = (float*)d_out;

    char* w = (char*)d_ws;
    auto alloc = [&](size_t bytes) -> char* {
        char* p = w;
        w += (bytes + 255) & ~(size_t)255;
        return p;
    };
    float* eo    = (float*)alloc((size_t)T_TOK * DIMM * 4);   // 2 MB
    float* mo    = (float*)alloc((size_t)T_TOK * DIMM * 4);   // 2 MB (contiguous with eo)
    float* hbuf  = (float*)alloc((size_t)2048 * EDIM * 4);    // 8 MB
    float* mlog  = (float*)alloc((size_t)T_TOK * NMIC * 4);   // 1.3 MB
    float* ewts  = (float*)alloc(2048 * 4);
    float* mtopp = (float*)alloc(8192 * 4);
    float* ep_w  = (float*)alloc(2048 * 4);
    float* mp_w  = (float*)alloc(8192 * 4);
    int*   eidx  = (int*)alloc(2048 * 4);
    int*   mtopi = (int*)alloc(8192 * 4);
    int*   cnts  = (int*)alloc((NEXP + NMIC) * 4);            // ecnt | mcnt contiguous
    int*   ecnt  = cnts;
    int*   mcnt  = cnts + NEXP;
    int*   eoff  = (int*)alloc((NEXP + 1) * 4);
    int*   ecur  = (int*)alloc(NEXP * 4);
    int*   moff  = (int*)alloc((NMIC + 1) * 4);
    int*   mcur  = (int*)alloc(NMIC * 4);
    int2*  etile = (int2*)alloc(E8TILES * 8);
    int2*  mtile = (int2*)alloc(MTILES * 8);
    int*   entile= (int*)alloc(4);
    int*   mntile= (int*)alloc(4);
    int*   ep_tok= (int*)alloc(2048 * 4);
    int*   mp_tok= (int*)alloc(8192 * 4);

    hipMemsetAsync(eo, 0, (size_t)2 * T_TOK * DIMM * 4, stream);   // eo + mo
    hipMemsetAsync(cnts, 0, (NEXP + NMIC) * 4, stream);

    k_router <<<T_TOK/4, 256, 0, stream>>>(x, rw, rb, eidx, ewts, ecnt);
    k_scan   <<<1, 512, 0, stream>>>(ecnt, NEXP, 8, eoff, ecur, etile, entile);
    k_scatter<<<(T_TOK*2 + 255)/256, 256, 0, stream>>>(eidx, ewts, T_TOK*2, 2, ecur, ep_tok, ep_w);
    k_effn1  <<<dim3(E8TILES, 4, 1), 256, 0, stream>>>(x, ew1, eb1, etile, entile, eoff, ep_tok, hbuf);
    k_effn2  <<<dim3(E8TILES, 2, 2), 256, 0, stream>>>(hbuf, ew2, eb2, etile, entile, eoff, ep_tok, ep_w, eo);
    k_mlog   <<<T_TOK/4, 384, 0, stream>>>(eo, mrw, mrb, mlog);
    k_mtop   <<<T_TOK/4, 256, 0, stream>>>(mlog, mtopi, mtopp, mcnt);
    k_scan   <<<1, 512, 0, stream>>>(mcnt, NMIC, 16, moff, mcur, mtile, mntile);
    k_scatter<<<(T_TOK*8 + 255)/256, 256, 0, stream>>>(mtopi, mtopp, T_TOK*8, 8, mcur, mp_tok, mp_w);
    k_micro  <<<MTILES, 256, 0, stream>>>(eo, mw1, mb1, mw2, mb2, mg, mbeta,
                                          mtile, mntile, moff, mp_tok, mp_w, mo);
    k_final  <<<T_TOK/4, 256, 0, stream>>>(eo, mo, ng, nb, out);
}